// Round 7
// baseline (114.061 us; speedup 1.0000x reference)
//
#include <hip/hip_runtime.h>

#define B 4
#define TE 512
#define TD 256
#define D 256

#define C2    2.8853900817779268f   // 2/ln(2): exp(2x) = exp2(C2*x)
#define LOG2E 1.4426950408889634f

// ---------------------------------------------------------------------------
// K1: projections + exp2.
//   ewt[b][d][e] = exp2(C2 * (enc@W_a)[b][e][d])   (TRANSPOSED, e contiguous)
//   eu [b][t][d] = exp2(C2 * (dec@U_a)[b][t][d])
// Blocks 0..255: enc (8 e-rows).  Blocks 256..383: dec (8 t-rows).
// Thread = output column. Full-K accumulation; A rows via LDS b128
// broadcasts; W via coalesced dword loads (column per thread).
// 8 rows/block halves W L2 re-reads vs 4 rows (96 MB total).
// ---------------------------------------------------------------------------
__global__ __launch_bounds__(256) void proj_kernel(
    const float* __restrict__ enc, const float* __restrict__ dec,
    const float* __restrict__ Wa,  const float* __restrict__ Ua,
    float* __restrict__ ewt, float* __restrict__ eu)
{
    __shared__ float a_lds[8 * 256];
    const int tid = threadIdx.x;
    const int blk = blockIdx.x;
    const bool is_enc = blk < 256;
    const float* __restrict__ A = is_enc ? enc : dec;
    const float* __restrict__ W = is_enc ? Wa  : Ua;
    const int row0 = (is_enc ? blk : blk - 256) * 8;

    {
        const float4* src = (const float4*)(A + (size_t)row0 * 256);
        ((float4*)a_lds)[tid]       = src[tid];
        ((float4*)a_lds)[tid + 256] = src[tid + 256];
    }
    __syncthreads();

    float acc[8] = {0.f,0.f,0.f,0.f,0.f,0.f,0.f,0.f};

    #pragma unroll 4
    for (int k = 0; k < 256; k += 4) {
        const float w0 = W[(k + 0) * 256 + tid];
        const float w1 = W[(k + 1) * 256 + tid];
        const float w2 = W[(k + 2) * 256 + tid];
        const float w3 = W[(k + 3) * 256 + tid];
        #pragma unroll
        for (int r = 0; r < 8; r++) {
            const float4 a4 = *(const float4*)&a_lds[r * 256 + k];
            acc[r] = fmaf(a4.x, w0, acc[r]);
            acc[r] = fmaf(a4.y, w1, acc[r]);
            acc[r] = fmaf(a4.z, w2, acc[r]);
            acc[r] = fmaf(a4.w, w3, acc[r]);
        }
    }

    float f[8];
    #pragma unroll
    for (int r = 0; r < 8; r++)
        f[r] = __builtin_amdgcn_exp2f(acc[r] * C2);

    if (is_enc) {
        const int b  = row0 >> 9;
        const int e0 = row0 & 511;
        float* o = ewt + ((size_t)(b * 256 + tid)) * 512 + e0;   // e-contig
        *(float4*)(o + 0) = make_float4(f[0], f[1], f[2], f[3]);
        *(float4*)(o + 4) = make_float4(f[4], f[5], f[6], f[7]);
    } else {
        #pragma unroll
        for (int r = 0; r < 8; r++)
            eu[(row0 + r) * 256 + tid] = f[r];
    }
}

// ---------------------------------------------------------------------------
// K2: raw scores.  score'[t][e] = -2 * sum_d v_d / (1 + Ew[d][e]*Eu[t][d])
// (the softmax-invariant +sum_d v_d term is dropped).
// grid 512 = (b, t-quad, e-half), 512 threads: tid>>8 = t-pair, tid&255 = e.
// 4096 waves = 4 waves/SIMD. Both t-pairs hit the same ewt lines (L1 reuse).
// ---------------------------------------------------------------------------
__global__ __launch_bounds__(512) void score_kernel(
    const float* __restrict__ ewt, const float* __restrict__ eu,
    const float* __restrict__ Va,  float* __restrict__ raw)
{
    __shared__ float eul[4 * 256];
    __shared__ float val[256];

    const int tid = threadIdx.x;
    const int b   = blockIdx.x >> 7;
    const int tq  = (blockIdx.x >> 1) & 63;
    const int eh  = blockIdx.x & 1;
    const int bt0 = b * 256 + tq * 4;

    if (tid < 256) val[tid] = Va[tid];
    {
        const float* __restrict__ src = eu + (size_t)bt0 * 256;
        eul[tid]       = src[tid];
        eul[tid + 512] = src[tid + 512];
    }
    __syncthreads();

    const int tp = tid >> 8;            // t-pair within quad
    const int e  = eh * 256 + (tid & 255);
    const float* __restrict__ ewb = ewt + (size_t)b * 256 * 512 + e;
    const float* __restrict__ ea0 = &eul[(2 * tp + 0) * 256];
    const float* __restrict__ ea1 = &eul[(2 * tp + 1) * 256];

    float q0 = 0.f, q1 = 0.f;

    #pragma unroll 4
    for (int d = 0; d < 256; d += 4) {
        const float w0 = ewb[(d + 0) * 512];
        const float w1 = ewb[(d + 1) * 512];
        const float w2 = ewb[(d + 2) * 512];
        const float w3 = ewb[(d + 3) * 512];
        const float4 v4 = *(const float4*)&val[d];
        const float4 a0 = *(const float4*)&ea0[d];
        const float4 a1 = *(const float4*)&ea1[d];

        q0 += v4.x * __builtin_amdgcn_rcpf(fmaf(w0, a0.x, 1.0f));
        q0 += v4.y * __builtin_amdgcn_rcpf(fmaf(w1, a0.y, 1.0f));
        q0 += v4.z * __builtin_amdgcn_rcpf(fmaf(w2, a0.z, 1.0f));
        q0 += v4.w * __builtin_amdgcn_rcpf(fmaf(w3, a0.w, 1.0f));

        q1 += v4.x * __builtin_amdgcn_rcpf(fmaf(w0, a1.x, 1.0f));
        q1 += v4.y * __builtin_amdgcn_rcpf(fmaf(w1, a1.y, 1.0f));
        q1 += v4.z * __builtin_amdgcn_rcpf(fmaf(w2, a1.z, 1.0f));
        q1 += v4.w * __builtin_amdgcn_rcpf(fmaf(w3, a1.w, 1.0f));
    }

    raw[((size_t)(bt0 + 2 * tp + 0)) * 512 + e] = -2.0f * q0;
    raw[((size_t)(bt0 + 2 * tp + 1)) * 512 + e] = -2.0f * q1;
}

// ---------------------------------------------------------------------------
// K3: softmax + context.  grid 512 = (b, t-quad, d-half), 256 threads.
// Softmax: wave w owns decoder row t0+w entirely (8 values/lane), pure
// shuffle reductions — no __syncthreads inside. Redundant across d-halves;
// only dh==0 writes aw.
// Context: thread = (e-group 2, d-lane 128); enc reads coalesced; weights
// broadcast from LDS; 2-way e-group combine through LDS.
// ---------------------------------------------------------------------------
__global__ __launch_bounds__(256) void sctx_kernel(
    const float* __restrict__ enc, const float* __restrict__ raw,
    float* __restrict__ ctx, float* __restrict__ aw)
{
    __shared__ float wlds[4][TE];
    __shared__ float part[2][4][128];

    const int tid = threadIdx.x;
    const int b   = blockIdx.x >> 7;
    const int tq  = (blockIdx.x >> 1) & 63;
    const int dh  = blockIdx.x & 1;
    const int bt0 = b * 256 + tq * 4;

    {   // ---- per-wave softmax: wave wv -> row t = wv ---------------------
        const int wv   = tid >> 6;
        const int lane = tid & 63;
        const float* __restrict__ rrow = raw + ((size_t)(bt0 + wv)) * 512;

        float x[8];
        #pragma unroll
        for (int j = 0; j < 8; j++) x[j] = rrow[lane + 64 * j];

        float m = x[0];
        #pragma unroll
        for (int j = 1; j < 8; j++) m = fmaxf(m, x[j]);
        #pragma unroll
        for (int s = 32; s > 0; s >>= 1) m = fmaxf(m, __shfl_xor(m, s, 64));

        float g[8], ssum = 0.f;
        #pragma unroll
        for (int j = 0; j < 8; j++) {
            g[j] = __builtin_amdgcn_exp2f((x[j] - m) * LOG2E);
            ssum += g[j];
        }
        #pragma unroll
        for (int s = 32; s > 0; s >>= 1) ssum += __shfl_xor(ssum, s, 64);
        const float inv = __builtin_amdgcn_rcpf(ssum);

        float* __restrict__ ao = aw + ((size_t)(bt0 + wv)) * 512;
        #pragma unroll
        for (int j = 0; j < 8; j++) {
            const float p = g[j] * inv;
            wlds[wv][lane + 64 * j] = p;
            if (dh == 0) ao[lane + 64 * j] = p;
        }
    }
    __syncthreads();

    // ---- context --------------------------------------------------------
    {
        const int eg = tid >> 7;           // e in [eg*256, eg*256+256)
        const int dl = tid & 127;          // d = dh*128 + dl
        const float* __restrict__ eb =
            enc + ((size_t)b * 512 + eg * 256) * 256 + dh * 128 + dl;
        const int e0 = eg * 256;

        float c0 = 0.f, c1 = 0.f, c2 = 0.f, c3 = 0.f;
        #pragma unroll 4
        for (int j = 0; j < 256; j += 4) {
            const float4 w0 = *(const float4*)&wlds[0][e0 + j];
            const float4 w1 = *(const float4*)&wlds[1][e0 + j];
            const float4 w2 = *(const float4*)&wlds[2][e0 + j];
            const float4 w3 = *(const float4*)&wlds[3][e0 + j];
            const float r0 = eb[(j + 0) * 256];
            const float r1 = eb[(j + 1) * 256];
            const float r2 = eb[(j + 2) * 256];
            const float r3 = eb[(j + 3) * 256];
            c0 = fmaf(w0.x, r0, c0); c0 = fmaf(w0.y, r1, c0); c0 = fmaf(w0.z, r2, c0); c0 = fmaf(w0.w, r3, c0);
            c1 = fmaf(w1.x, r0, c1); c1 = fmaf(w1.y, r1, c1); c1 = fmaf(w1.z, r2, c1); c1 = fmaf(w1.w, r3, c1);
            c2 = fmaf(w2.x, r0, c2); c2 = fmaf(w2.y, r1, c2); c2 = fmaf(w2.z, r2, c2); c2 = fmaf(w2.w, r3, c2);
            c3 = fmaf(w3.x, r0, c3); c3 = fmaf(w3.y, r1, c3); c3 = fmaf(w3.z, r2, c3); c3 = fmaf(w3.w, r3, c3);
        }
        part[eg][0][dl] = c0;
        part[eg][1][dl] = c1;
        part[eg][2][dl] = c2;
        part[eg][3][dl] = c3;
    }
    __syncthreads();

    {
        const int th = tid >> 7;            // 0..1
        const int dl = tid & 127;
        #pragma unroll
        for (int p = 0; p < 2; p++) {
            const int t = p * 2 + th;
            ctx[((size_t)(bt0 + t)) * 256 + dh * 128 + dl] =
                part[0][t][dl] + part[1][t][dl];
        }
    }
}

extern "C" void kernel_launch(void* const* d_in, const int* in_sizes, int n_in,
                              void* d_out, int out_size, void* d_ws, size_t ws_size,
                              hipStream_t stream) {
    const float* enc = (const float*)d_in[0];   // [4,512,256]
    const float* dec = (const float*)d_in[1];   // [4,256,256]
    const float* Wa  = (const float*)d_in[2];   // [256,256]
    const float* Ua  = (const float*)d_in[3];   // [256,256]
    const float* Va  = (const float*)d_in[4];   // [256,1]

    float* out = (float*)d_out;
    float* ctx = out;                           // [4,256,256]
    float* aw  = out + B * TD * D;              // [4,256,512]

    float* ewt = (float*)d_ws;                  // [4][256 d][512 e]  2 MB
    float* eu  = ewt + (size_t)B * D * TE;      // [4][256 t][256 d]  1 MB
    float* raw = eu  + (size_t)B * TD * D;      // [4][256 t][512 e]  2 MB

    proj_kernel <<<dim3(384), dim3(256), 0, stream>>>(enc, dec, Wa, Ua, ewt, eu);
    score_kernel<<<dim3(512), dim3(512), 0, stream>>>(ewt, eu, Va, raw);
    sctx_kernel <<<dim3(512), dim3(256), 0, stream>>>(enc, raw, ctx, aw);
}

// Round 8
// 113.012 us; speedup vs baseline: 1.0093x; 1.0093x over previous
//
#include <hip/hip_runtime.h>

#define B 4
#define TE 512
#define TD 256
#define D 256

#define C2    2.8853900817779268f   // 2/ln(2): exp(2x) = exp2(C2*x)
#define LOG2E 1.4426950408889634f

// ---------------------------------------------------------------------------
// K1: projections + exp2.
//   ewt[b][d][e] = exp2(C2 * (enc@W_a)[b][e][d])   (TRANSPOSED, e contiguous)
//   eu [b][t][d] = exp2(C2 * (dec@U_a)[b][t][d])
// 384 blocks x 512 threads (3 waves/SIMD). 8 rows/block; thread = (row-half,
// col): rh = tid>>8 handles 4 rows, col = tid&255. Threads 256..511 read the
// same W addresses as 0..255 -> L1 broadcast; W L2 traffic stays 96 MB.
// ---------------------------------------------------------------------------
__global__ __launch_bounds__(512) void proj_kernel(
    const float* __restrict__ enc, const float* __restrict__ dec,
    const float* __restrict__ Wa,  const float* __restrict__ Ua,
    float* __restrict__ ewt, float* __restrict__ eu)
{
    __shared__ float a_lds[8 * 256];
    const int tid = threadIdx.x;
    const int blk = blockIdx.x;
    const bool is_enc = blk < 256;
    const float* __restrict__ A = is_enc ? enc : dec;
    const float* __restrict__ W = is_enc ? Wa  : Ua;
    const int row0 = (is_enc ? blk : blk - 256) * 8;

    ((float4*)a_lds)[tid] = ((const float4*)(A + (size_t)row0 * 256))[tid];
    __syncthreads();

    const int rh  = tid >> 8;      // 0..1 -> rows rh*4 .. rh*4+3
    const int col = tid & 255;

    float c0 = 0.f, c1 = 0.f, c2 = 0.f, c3 = 0.f;
    const float* __restrict__ ar = &a_lds[rh * 4 * 256];

    #pragma unroll 4
    for (int k = 0; k < 256; k += 4) {
        const float w0 = W[(k + 0) * 256 + col];
        const float w1 = W[(k + 1) * 256 + col];
        const float w2 = W[(k + 2) * 256 + col];
        const float w3 = W[(k + 3) * 256 + col];
        const float4 a0 = *(const float4*)&ar[0 * 256 + k];
        const float4 a1 = *(const float4*)&ar[1 * 256 + k];
        const float4 a2 = *(const float4*)&ar[2 * 256 + k];
        const float4 a3 = *(const float4*)&ar[3 * 256 + k];
        c0 = fmaf(a0.x, w0, c0); c0 = fmaf(a0.y, w1, c0); c0 = fmaf(a0.z, w2, c0); c0 = fmaf(a0.w, w3, c0);
        c1 = fmaf(a1.x, w0, c1); c1 = fmaf(a1.y, w1, c1); c1 = fmaf(a1.z, w2, c1); c1 = fmaf(a1.w, w3, c1);
        c2 = fmaf(a2.x, w0, c2); c2 = fmaf(a2.y, w1, c2); c2 = fmaf(a2.z, w2, c2); c2 = fmaf(a2.w, w3, c2);
        c3 = fmaf(a3.x, w0, c3); c3 = fmaf(a3.y, w1, c3); c3 = fmaf(a3.z, w2, c3); c3 = fmaf(a3.w, w3, c3);
    }

    float4 f;
    f.x = __builtin_amdgcn_exp2f(c0 * C2);
    f.y = __builtin_amdgcn_exp2f(c1 * C2);
    f.z = __builtin_amdgcn_exp2f(c2 * C2);
    f.w = __builtin_amdgcn_exp2f(c3 * C2);

    if (is_enc) {
        const int b  = row0 >> 9;
        const int e0 = (row0 & 511) + rh * 4;
        *(float4*)&ewt[((size_t)(b * 256 + col)) * 512 + e0] = f;   // e-contig
    } else {
        const int r0 = row0 + rh * 4;
        eu[(r0 + 0) * 256 + col] = f.x;
        eu[(r0 + 1) * 256 + col] = f.y;
        eu[(r0 + 2) * 256 + col] = f.z;
        eu[(r0 + 3) * 256 + col] = f.w;
    }
}

// ---------------------------------------------------------------------------
// K2: fused score + softmax + context.  One block per (b, t-pair):
// 512 blocks x 512 threads = 4 waves/SIMD, 2 blocks/CU (barriers overlap).
// Score: thread = e; per d: 1 ewt load shared by both t's; unroll 8 keeps
//        8 loads in flight (latency cover). score' = -2 * sum_d v/(1+Ew*Eu).
// Softmax: 4 waves per t, shuffle reduce + tiny LDS combine.
// Context: thread = (e-group, d); 2-way e-group combine through LDS.
// ---------------------------------------------------------------------------
__global__ __launch_bounds__(512) void attn_kernel(
    const float* __restrict__ enc, const float* __restrict__ ewt,
    const float* __restrict__ eu,  const float* __restrict__ Va,
    float* __restrict__ ctx, float* __restrict__ aw)
{
    __shared__ float eul[2 * 256];     // Eu rows t0, t0+1
    __shared__ float val[256];         // Va
    __shared__ float sc[2][TE];        // scores -> weights
    __shared__ float wred[2][2][4];    // [phase][t][wave-seg]
    __shared__ float part[2][2][256];  // [e-group][t][d]

    const int tid = threadIdx.x;
    const int b   = blockIdx.x >> 7;
    const int tp  = blockIdx.x & 127;
    const int bt0 = b * 256 + tp * 2;

    if (tid < 256) val[tid] = Va[tid];
    eul[tid] = eu[(size_t)bt0 * 256 + tid];
    __syncthreads();

    // ---- scores (thread = e) -------------------------------------------
    {
        const float* __restrict__ ewb = ewt + (size_t)b * 256 * 512 + tid;
        float q0 = 0.f, q1 = 0.f;

        for (int d = 0; d < 256; d += 8) {
            float w[8];
            #pragma unroll
            for (int j = 0; j < 8; j++) w[j] = ewb[(d + j) * 512];

            #pragma unroll
            for (int h = 0; h < 2; h++) {
                const int dd = d + h * 4;
                const float4 v4 = *(const float4*)&val[dd];
                const float4 a0 = *(const float4*)&eul[dd];
                const float4 a1 = *(const float4*)&eul[256 + dd];
                const float* wj = &w[h * 4];

                q0 += v4.x * __builtin_amdgcn_rcpf(fmaf(wj[0], a0.x, 1.0f));
                q0 += v4.y * __builtin_amdgcn_rcpf(fmaf(wj[1], a0.y, 1.0f));
                q0 += v4.z * __builtin_amdgcn_rcpf(fmaf(wj[2], a0.z, 1.0f));
                q0 += v4.w * __builtin_amdgcn_rcpf(fmaf(wj[3], a0.w, 1.0f));

                q1 += v4.x * __builtin_amdgcn_rcpf(fmaf(wj[0], a1.x, 1.0f));
                q1 += v4.y * __builtin_amdgcn_rcpf(fmaf(wj[1], a1.y, 1.0f));
                q1 += v4.z * __builtin_amdgcn_rcpf(fmaf(wj[2], a1.z, 1.0f));
                q1 += v4.w * __builtin_amdgcn_rcpf(fmaf(wj[3], a1.w, 1.0f));
            }
        }
        sc[0][tid] = -2.0f * q0;
        sc[1][tid] = -2.0f * q1;
    }
    __syncthreads();

    // ---- softmax: waves 0-3 -> t=0, waves 4-7 -> t=1 --------------------
    {
        const int wv   = tid >> 6;
        const int lane = tid & 63;
        const int t    = wv >> 2;
        const int seg  = wv & 3;
        float* __restrict__ srow = &sc[t][seg * 128];

        const float x0 = srow[lane];
        const float x1 = srow[lane + 64];

        float m = fmaxf(x0, x1);
        #pragma unroll
        for (int s = 32; s > 0; s >>= 1) m = fmaxf(m, __shfl_xor(m, s, 64));
        if (lane == 0) wred[0][t][seg] = m;
        __syncthreads();
        const float4 mm = *(const float4*)&wred[0][t][0];
        const float M = fmaxf(fmaxf(mm.x, mm.y), fmaxf(mm.z, mm.w));

        const float g0 = __builtin_amdgcn_exp2f((x0 - M) * LOG2E);
        const float g1 = __builtin_amdgcn_exp2f((x1 - M) * LOG2E);

        float ssum = g0 + g1;
        #pragma unroll
        for (int s = 32; s > 0; s >>= 1) ssum += __shfl_xor(ssum, s, 64);
        if (lane == 0) wred[1][t][seg] = ssum;
        __syncthreads();
        const float4 sm = *(const float4*)&wred[1][t][0];
        const float inv = __builtin_amdgcn_rcpf((sm.x + sm.y) + (sm.z + sm.w));

        const float p0 = g0 * inv, p1 = g1 * inv;
        srow[lane]      = p0;
        srow[lane + 64] = p1;
        float* __restrict__ ao = aw + ((size_t)(bt0 + t)) * 512 + seg * 128;
        ao[lane]      = p0;
        ao[lane + 64] = p1;
    }
    __syncthreads();

    // ---- context: thread = (e-group, d) --------------------------------
    {
        const int eg = tid >> 8;       // e in [eg*256, eg*256+256)
        const int dl = tid & 255;
        const float* __restrict__ eb =
            enc + ((size_t)b * 512 + eg * 256) * 256 + dl;
        const int e0 = eg * 256;

        float c0 = 0.f, c1 = 0.f;
        #pragma unroll 2
        for (int j = 0; j < 256; j += 8) {
            float r[8];
            #pragma unroll
            for (int u = 0; u < 8; u++) r[u] = eb[(j + u) * 256];
            #pragma unroll
            for (int h = 0; h < 2; h++) {
                const float4 w0 = *(const float4*)&sc[0][e0 + j + h * 4];
                const float4 w1 = *(const float4*)&sc[1][e0 + j + h * 4];
                const float* ru = &r[h * 4];
                c0 = fmaf(w0.x, ru[0], c0); c0 = fmaf(w0.y, ru[1], c0);
                c0 = fmaf(w0.z, ru[2], c0); c0 = fmaf(w0.w, ru[3], c0);
                c1 = fmaf(w1.x, ru[0], c1); c1 = fmaf(w1.y, ru[1], c1);
                c1 = fmaf(w1.z, ru[2], c1); c1 = fmaf(w1.w, ru[3], c1);
            }
        }
        part[eg][0][dl] = c0;
        part[eg][1][dl] = c1;
    }
    __syncthreads();

    {
        const int t  = tid >> 8;       // 0..1
        const int dl = tid & 255;
        ctx[((size_t)(bt0 + t)) * 256 + dl] = part[0][t][dl] + part[1][t][dl];
    }
}

extern "C" void kernel_launch(void* const* d_in, const int* in_sizes, int n_in,
                              void* d_out, int out_size, void* d_ws, size_t ws_size,
                              hipStream_t stream) {
    const float* enc = (const float*)d_in[0];   // [4,512,256]
    const float* dec = (const float*)d_in[1];   // [4,256,256]
    const float* Wa  = (const float*)d_in[2];   // [256,256]
    const float* Ua  = (const float*)d_in[3];   // [256,256]
    const float* Va  = (const float*)d_in[4];   // [256,1]

    float* out = (float*)d_out;
    float* ctx = out;                           // [4,256,256]
    float* aw  = out + B * TD * D;              // [4,256,512]

    float* ewt = (float*)d_ws;                  // [4][256 d][512 e]  2 MB
    float* eu  = ewt + (size_t)B * D * TE;      // [4][256 t][256 d]  1 MB

    proj_kernel<<<dim3(384), dim3(512), 0, stream>>>(enc, dec, Wa, Ua, ewt, eu);
    attn_kernel<<<dim3(512), dim3(512), 0, stream>>>(enc, ewt, eu, Va, ctx, aw);
}

// Round 9
// 106.457 us; speedup vs baseline: 1.0714x; 1.0616x over previous
//
#include <hip/hip_runtime.h>

#define B 4
#define TE 512
#define TD 256
#define D 256

#define C2    2.8853900817779268f   // 2/ln(2): exp(2x) = exp2(C2*x)
#define LOG2E 1.4426950408889634f

// ---------------------------------------------------------------------------
// K1: projections + exp2 (unchanged from the 106.6 µs build).
//   ewt[b][d][e] = exp2(C2 * (enc@W_a)[b][e][d])   (TRANSPOSED, e contiguous)
//   eu [b][t][d] = exp2(C2 * (dec@U_a)[b][t][d])
// ---------------------------------------------------------------------------
__global__ __launch_bounds__(256) void proj_kernel(
    const float* __restrict__ enc, const float* __restrict__ dec,
    const float* __restrict__ Wa,  const float* __restrict__ Ua,
    float* __restrict__ ewt, float* __restrict__ eu)
{
    __shared__ float a_lds[8 * 256];
    const int tid = threadIdx.x;
    const int blk = blockIdx.x;
    const bool is_enc = blk < 256;
    const float* __restrict__ A = is_enc ? enc : dec;
    const float* __restrict__ W = is_enc ? Wa  : Ua;
    const int row0 = (is_enc ? blk : blk - 256) * 8;

    {
        const float4* src = (const float4*)(A + (size_t)row0 * 256);
        ((float4*)a_lds)[tid]       = src[tid];
        ((float4*)a_lds)[tid + 256] = src[tid + 256];
    }
    __syncthreads();

    float acc[8] = {0.f,0.f,0.f,0.f,0.f,0.f,0.f,0.f};

    #pragma unroll 4
    for (int k = 0; k < 256; k += 4) {
        const float w0 = W[(k + 0) * 256 + tid];
        const float w1 = W[(k + 1) * 256 + tid];
        const float w2 = W[(k + 2) * 256 + tid];
        const float w3 = W[(k + 3) * 256 + tid];
        #pragma unroll
        for (int r = 0; r < 8; r++) {
            const float4 a4 = *(const float4*)&a_lds[r * 256 + k];
            acc[r] = fmaf(a4.x, w0, acc[r]);
            acc[r] = fmaf(a4.y, w1, acc[r]);
            acc[r] = fmaf(a4.z, w2, acc[r]);
            acc[r] = fmaf(a4.w, w3, acc[r]);
        }
    }

    float f[8];
    #pragma unroll
    for (int r = 0; r < 8; r++)
        f[r] = __builtin_amdgcn_exp2f(acc[r] * C2);

    if (is_enc) {
        const int b  = row0 >> 9;
        const int e0 = row0 & 511;
        float* o = ewt + ((size_t)(b * 256 + tid)) * 512 + e0;   // e-contig
        *(float4*)(o + 0) = make_float4(f[0], f[1], f[2], f[3]);
        *(float4*)(o + 4) = make_float4(f[4], f[5], f[6], f[7]);
    } else {
        #pragma unroll
        for (int r = 0; r < 8; r++)
            eu[(row0 + r) * 256 + tid] = f[r];
    }
}

// 4-way division combine: returns q += sum_i v_i / p_i  with ONE rcp.
__device__ __forceinline__ void qcomb4(float& q, const float4& v,
                                       float p0, float p1, float p2, float p3)
{
    const float n01 = fmaf(v.y, p0, v.x * p1);
    const float d01 = p0 * p1;
    const float n23 = fmaf(v.w, p2, v.z * p3);
    const float d23 = p2 * p3;
    const float num = fmaf(n23, d01, n01 * d23);
    const float den = d01 * d23;
    q = fmaf(num, __builtin_amdgcn_rcpf(den), q);
}

// ---------------------------------------------------------------------------
// K2: fused score + softmax + context.  One block per (b, t-quad):
// 256 blocks x 1024 threads = 16 waves/CU = 4 waves/SIMD.
// Score: e = tid&511, thread-half tp = tid>>9 owns t-pair {2tp, 2tp+1}.
//   Both halves read identical ewt addresses in lockstep (L1 broadcast), so
//   L2 traffic matches the t-quad/512-thread layout.
//   score'[t][e] = -2 * sum_d v_d/(1+Ew*Eu), via 4-way rcp-combining
//   (4x fewer v_rcp_f32 — the measured bottleneck).
// Softmax: wave wv: t = wv>>2, seg = wv&3; shuffle + tiny LDS combine.
// Context: eg = tid>>8 covers 128 e's; dl = tid&255; 4-way LDS combine.
// ---------------------------------------------------------------------------
__global__ __launch_bounds__(1024) void attn_kernel(
    const float* __restrict__ enc, const float* __restrict__ ewt,
    const float* __restrict__ eu,  const float* __restrict__ Va,
    float* __restrict__ ctx, float* __restrict__ aw)
{
    __shared__ float eul[4 * 256];      // 4 Eu rows
    __shared__ float val[256];          // Va
    __shared__ float sc[4][TE];         // scores -> weights (8 KB)
    __shared__ float wred[2][4][4];     // [phase][t][seg]
    __shared__ float part[4][4][256];   // [e-group][t][d] (16 KB)

    const int tid = threadIdx.x;
    const int b   = blockIdx.x >> 6;
    const int t0  = (blockIdx.x & 63) * 4;
    const int bt0 = b * 256 + t0;

    if (tid < 256) val[tid] = Va[tid];
    eul[tid] = eu[(size_t)bt0 * 256 + tid];
    __syncthreads();

    // ---- scores ---------------------------------------------------------
    {
        const int e  = tid & 511;
        const int tp = tid >> 9;                  // 0..1 -> t-pair
        const float* __restrict__ ewb = ewt + (size_t)b * 256 * 512 + e;
        const float* __restrict__ ea0 = &eul[(2 * tp + 0) * 256];
        const float* __restrict__ ea1 = &eul[(2 * tp + 1) * 256];

        float q0 = 0.f, q1 = 0.f;

        for (int d = 0; d < 256; d += 8) {
            float w[8];
            #pragma unroll
            for (int j = 0; j < 8; j++) w[j] = ewb[(d + j) * 512];

            #pragma unroll
            for (int h = 0; h < 2; h++) {
                const int dd = d + h * 4;
                const float4 v4 = *(const float4*)&val[dd];
                const float4 a0 = *(const float4*)&ea0[dd];
                const float4 a1 = *(const float4*)&ea1[dd];
                const float* wj = &w[h * 4];

                qcomb4(q0, v4,
                       fmaf(wj[0], a0.x, 1.0f), fmaf(wj[1], a0.y, 1.0f),
                       fmaf(wj[2], a0.z, 1.0f), fmaf(wj[3], a0.w, 1.0f));
                qcomb4(q1, v4,
                       fmaf(wj[0], a1.x, 1.0f), fmaf(wj[1], a1.y, 1.0f),
                       fmaf(wj[2], a1.z, 1.0f), fmaf(wj[3], a1.w, 1.0f));
            }
        }
        sc[2 * tp + 0][e] = -2.0f * q0;
        sc[2 * tp + 1][e] = -2.0f * q1;
    }
    __syncthreads();

    // ---- softmax: wave wv -> (t = wv>>2, seg = wv&3) --------------------
    {
        const int wv   = tid >> 6;
        const int lane = tid & 63;
        const int t    = wv >> 2;
        const int seg  = wv & 3;
        float* __restrict__ srow = &sc[t][seg * 128];

        const float x0 = srow[lane];
        const float x1 = srow[lane + 64];

        float m = fmaxf(x0, x1);
        #pragma unroll
        for (int s = 32; s > 0; s >>= 1) m = fmaxf(m, __shfl_xor(m, s, 64));
        if (lane == 0) wred[0][t][seg] = m;
        __syncthreads();
        const float4 mm = *(const float4*)&wred[0][t][0];
        const float M = fmaxf(fmaxf(mm.x, mm.y), fmaxf(mm.z, mm.w));

        const float g0 = __builtin_amdgcn_exp2f((x0 - M) * LOG2E);
        const float g1 = __builtin_amdgcn_exp2f((x1 - M) * LOG2E);

        float ssum = g0 + g1;
        #pragma unroll
        for (int s = 32; s > 0; s >>= 1) ssum += __shfl_xor(ssum, s, 64);
        if (lane == 0) wred[1][t][seg] = ssum;
        __syncthreads();
        const float4 sm = *(const float4*)&wred[1][t][0];
        const float inv = __builtin_amdgcn_rcpf((sm.x + sm.y) + (sm.z + sm.w));

        const float p0 = g0 * inv, p1 = g1 * inv;
        srow[lane]      = p0;
        srow[lane + 64] = p1;
        float* __restrict__ ao = aw + ((size_t)(bt0 + t)) * 512 + seg * 128;
        ao[lane]      = p0;
        ao[lane + 64] = p1;
    }
    __syncthreads();

    // ---- context: eg = tid>>8 (128 e's each), dl = tid&255 --------------
    {
        const int eg = tid >> 8;
        const int dl = tid & 255;
        const float* __restrict__ eb =
            enc + ((size_t)b * 512 + eg * 128) * 256 + dl;
        const int e0 = eg * 128;

        float c0 = 0.f, c1 = 0.f, c2 = 0.f, c3 = 0.f;
        #pragma unroll 4
        for (int j = 0; j < 128; j += 4) {
            const float4 w0 = *(const float4*)&sc[0][e0 + j];
            const float4 w1 = *(const float4*)&sc[1][e0 + j];
            const float4 w2 = *(const float4*)&sc[2][e0 + j];
            const float4 w3 = *(const float4*)&sc[3][e0 + j];
            const float r0 = eb[(j + 0) * 256];
            const float r1 = eb[(j + 1) * 256];
            const float r2 = eb[(j + 2) * 256];
            const float r3 = eb[(j + 3) * 256];
            c0 = fmaf(w0.x, r0, c0); c0 = fmaf(w0.y, r1, c0); c0 = fmaf(w0.z, r2, c0); c0 = fmaf(w0.w, r3, c0);
            c1 = fmaf(w1.x, r0, c1); c1 = fmaf(w1.y, r1, c1); c1 = fmaf(w1.z, r2, c1); c1 = fmaf(w1.w, r3, c1);
            c2 = fmaf(w2.x, r0, c2); c2 = fmaf(w2.y, r1, c2); c2 = fmaf(w2.z, r2, c2); c2 = fmaf(w2.w, r3, c2);
            c3 = fmaf(w3.x, r0, c3); c3 = fmaf(w3.y, r1, c3); c3 = fmaf(w3.z, r2, c3); c3 = fmaf(w3.w, r3, c3);
        }
        part[eg][0][dl] = c0;
        part[eg][1][dl] = c1;
        part[eg][2][dl] = c2;
        part[eg][3][dl] = c3;
    }
    __syncthreads();

    {
        const int t  = tid >> 8;       // 0..3
        const int dl = tid & 255;
        ctx[((size_t)(bt0 + t)) * 256 + dl] =
            (part[0][t][dl] + part[1][t][dl]) +
            (part[2][t][dl] + part[3][t][dl]);
    }
}

extern "C" void kernel_launch(void* const* d_in, const int* in_sizes, int n_in,
                              void* d_out, int out_size, void* d_ws, size_t ws_size,
                              hipStream_t stream) {
    const float* enc = (const float*)d_in[0];   // [4,512,256]
    const float* dec = (const float*)d_in[1];   // [4,256,256]
    const float* Wa  = (const float*)d_in[2];   // [256,256]
    const float* Ua  = (const float*)d_in[3];   // [256,256]
    const float* Va  = (const float*)d_in[4];   // [256,1]

    float* out = (float*)d_out;
    float* ctx = out;                           // [4,256,256]
    float* aw  = out + B * TD * D;              // [4,256,512]

    float* ewt = (float*)d_ws;                  // [4][256 d][512 e]  2 MB
    float* eu  = ewt + (size_t)B * D * TE;      // [4][256 t][256 d]  1 MB

    proj_kernel<<<dim3(384), dim3(256), 0, stream>>>(enc, dec, Wa, Ua, ewt, eu);
    attn_kernel<<<dim3(256), dim3(1024), 0, stream>>>(enc, ewt, eu, Va, ctx, aw);
}